// Round 18
// baseline (50.717 us; speedup 1.0000x reference)
//
#include <hip/hip_runtime.h>

// Conv2d 5x5, C=3, O=1, stride 1, pad 2, N=256, H=W=224, +bias.
// R18 = R17 scaled once more: BAND=32, thread = 4col x 8row.
//   The R15->R17 lever (bigger band => fewer barriers, less stage halo,
//   fewer ds_reads/output) gave 53.4->45.0. Iterate it:
//   - reads/output/ch: 1.5 -> 1.125 (12 jj-rows feed 8 output rows)
//   - stage halo: 1.25x -> 1.125x (36 rows staged per 32 output rows)
//   - barriers: 3 per 32 output rows (vs 3 per 16)
//   - cost: dbuf 2x33408 = 66816 B -> 2 blocks/CU (the gamble; R13's 2-block
//     failure had 6 barriers + short phases; here 3 barriers, ~3200cyc phases
//     cover the ~900cyc stage latency inside one phase)
// Kept from R17: 4c read addressing (covers all 8 bank-quads evenly - bank
// clean), RST=232 (232%32=8 row rotation), +4-dword shifted rows, channel-
// phase pipeline with literal phases, 224/256 active threads, XCD swizzle,
// no launch_bounds min-arg.

namespace {

constexpr int Hc = 224, Wc = 224, Cc = 3;
constexpr int HW = Hc * Wc;
constexpr int CHW = Cc * HW;
constexpr int BAND = 32;              // output rows per band (= per block)
constexpr int SROWS = BAND + 4;       // 36 staged rows per (band, channel)
constexpr int RST = 232;              // LDS row stride (dwords); 232%32 = 8
constexpr int BUFD = SROWS * RST;     // 8352 dwords = 33408 B per buffer
constexpr int SPI = Hc / BAND;        // 7 bands (strips) per image
constexpr int BLK = 256;
constexpr int TROWS = 8;              // output rows per thread

__device__ __forceinline__ void gl_lds16(const float* g, float* l) {
  __builtin_amdgcn_global_load_lds(
      (const __attribute__((address_space(1))) void*)g,
      (__attribute__((address_space(3))) void*)l, 16, 0, 0);
}

__global__ __launch_bounds__(BLK) void conv5x5_r18(
    const float* __restrict__ x, const float* __restrict__ wl,
    const float* __restrict__ bptr, float* __restrict__ out) {
  __shared__ __align__(16) float sm[2 * BUFD];   // 66816 B

  const int tid = threadIdx.x;
  const int lane = tid & 63;
  const int wv = tid >> 6;

  // Bijective XCD swizzle: 1792 = 8 * 224.
  const int cpx = gridDim.x >> 3;
  const int bid = (blockIdx.x & 7) * cpx + (blockIdx.x >> 3);
  const int n = bid / SPI;                 // image
  const int band = bid % SPI;              // band index (32 rows)

  // Weights: wave-uniform, compile-time offsets -> SGPRs.
  float w[Cc][5][5];
#pragma unroll
  for (int c = 0; c < Cc; ++c)
#pragma unroll
    for (int i = 0; i < 25; ++i) w[c][i / 5][i % 5] = wl[c * 25 + i];
  const float bias = bptr[0];

  const float* xn = x + (size_t)n * CHW;
  float* outn = out + (size_t)n * HW;

  // Compute roles: 224 threads = 56 cols x 4 row-groups; thread = 4x8 outputs.
  const bool active = tid < 224;
  const int col = tid % 56;
  const int tg = tid / 56;
  const bool lo = (col == 0), hi = (col == 55);
  const int rdo = col * 4;                 // read base (dwords) within a row

  float4 acc[TROWS];                       // 8 output rows, live across phases

  // Stage phase P (literal): 36 rows of channel P, band `band`, into buffer
  // P&1. Wave wv owns rows {wv + 4i, i=0..8}. LDS dest is the wave-uniform
  // row base (+4-dword shift); HW adds lane*16 (lanes >= 56 masked; row data
  // = dwords 4..227, global dword j at LDS dword j+4). OOB rows (y pad:
  // band 0 r<2, band 6 r>=34) zero-filled.
#define STAGE_P(P)                                                            \
  do {                                                                        \
    const float* gch_ = xn + (size_t)(P) * HW;                                \
    float* smb_ = sm + ((P) & 1) * BUFD;                                      \
    _Pragma("unroll") for (int i_ = 0; i_ < 9; ++i_) {                        \
      const int r_ = wv + 4 * i_;                                             \
      const int gy_ = band * BAND - 2 + r_;                                   \
      float* ld_ = smb_ + r_ * RST + 4;                                       \
      if (gy_ >= 0 && gy_ < Hc) {                                             \
        if (lane < 56)                                                        \
          gl_lds16(gch_ + (size_t)gy_ * Wc + lane * 4, ld_);                  \
      } else {                                                                \
        if (lane < 56)                                                        \
          *(float4*)(ld_ + lane * 4) = make_float4(0.f, 0.f, 0.f, 0.f);       \
      }                                                                       \
    }                                                                         \
  } while (0)

  // Compute phase P (literal) from buffer P&1. Thread reads LDS rows
  // tg*8 + jj, jj=0..11; output row r (0..7) taps jj = r..r+4 (ky = jj-r).
  // Window = 3 aligned b128: A @ dword 4c, B @ 4c+4, C @ 4c+8;
  // win[j] = global[4c-2+j] = {A.z,A.w,B.xyzw,C.x,C.y}; lo/hi masked.
#define COMPUTE_P(P)                                                          \
  do {                                                                        \
    constexpr int ch_ = (P);                                                  \
    const float* smb_ = sm + ((P) & 1) * BUFD;                                \
    if (ch_ == 0) {                                                           \
      _Pragma("unroll") for (int r_ = 0; r_ < TROWS; ++r_)                    \
          acc[r_] = make_float4(0.f, 0.f, 0.f, 0.f);                          \
    }                                                                         \
    if (active) {                                                             \
      _Pragma("unroll") for (int jj_ = 0; jj_ < TROWS + 4; ++jj_) {           \
        const float* rp_ = smb_ + (tg * TROWS + jj_) * RST + rdo;             \
        const float4 A_ = *(const float4*)rp_;                                \
        const float4 B_ = *(const float4*)(rp_ + 4);                          \
        const float4 C_ = *(const float4*)(rp_ + 8);                          \
        float win_[8];                                                        \
        win_[0] = lo ? 0.f : A_.z;                                            \
        win_[1] = lo ? 0.f : A_.w;                                            \
        win_[2] = B_.x; win_[3] = B_.y; win_[4] = B_.z; win_[5] = B_.w;       \
        win_[6] = hi ? 0.f : C_.x;                                            \
        win_[7] = hi ? 0.f : C_.y;                                            \
        _Pragma("unroll") for (int r_ = 0; r_ < TROWS; ++r_) {                \
          if (r_ <= jj_ && jj_ - r_ <= 4) {                                   \
            _Pragma("unroll") for (int kx_ = 0; kx_ < 5; ++kx_) {             \
              const float wv_ = w[ch_][jj_ - r_][kx_];                        \
              acc[r_].x = fmaf(win_[kx_ + 0], wv_, acc[r_].x);                \
              acc[r_].y = fmaf(win_[kx_ + 1], wv_, acc[r_].y);                \
              acc[r_].z = fmaf(win_[kx_ + 2], wv_, acc[r_].z);                \
              acc[r_].w = fmaf(win_[kx_ + 3], wv_, acc[r_].w);                \
            }                                                                 \
          }                                                                   \
        }                                                                     \
      }                                                                       \
      if (ch_ == 2) {                                                         \
        const int gy0_ = band * BAND + tg * TROWS;                            \
        float* op_ = outn + (size_t)gy0_ * Wc + col * 4;                      \
        _Pragma("unroll") for (int r_ = 0; r_ < TROWS; ++r_) {                \
          float4 oo_;                                                         \
          oo_.x = acc[r_].x + bias; oo_.y = acc[r_].y + bias;                 \
          oo_.z = acc[r_].z + bias; oo_.w = acc[r_].w + bias;                 \
          *(float4*)(op_ + (size_t)r_ * Wc) = oo_;                            \
        }                                                                     \
      }                                                                       \
    }                                                                         \
  } while (0)

  // ---- pipeline: stage(P+1) flies under compute(P); 3 barriers total ----
  STAGE_P(0);
  __syncthreads(); STAGE_P(1); COMPUTE_P(0);
  __syncthreads(); STAGE_P(2); COMPUTE_P(1);
  __syncthreads();             COMPUTE_P(2);

#undef STAGE_P
#undef COMPUTE_P
}

}  // namespace

extern "C" void kernel_launch(void* const* d_in, const int* in_sizes, int n_in,
                              void* d_out, int out_size, void* d_ws, size_t ws_size,
                              hipStream_t stream) {
  const float* x  = (const float*)d_in[0];   // [N,3,224,224] f32
  const float* wl = (const float*)d_in[1];   // [1,75] f32
  const float* b  = (const float*)d_in[2];   // [1] f32
  float* out = (float*)d_out;                // [N,224,224] f32

  const int N = out_size / HW;               // 256
  const int nblk = N * SPI;                  // 1792 = 8 * 224

  conv5x5_r18<<<nblk, BLK, 0, stream>>>(x, wl, b, out);
}

// Round 19
// 48.636 us; speedup vs baseline: 1.0428x; 1.0428x over previous
//
#include <hip/hip_runtime.h>

// Conv2d 5x5, C=3, O=1, stride 1, pad 2, N=256, H=W=224, +bias.
// R19: BAND=32 with BLK=512 -> 16 waves/CU restored.
//   R18 post-mortem: the 50.7 regression was waves/CU halving (2 blocks x 4
//   waves = 8 vs R17's 16), not BAND=32 itself. HBM needs ~16 waves of
//   staggered stage requests. R17 runs at ~86% of its staged-traffic floor
//   (242 MB ~ 38.5us); BAND=32 cuts the floor to ~227 MB ~ 36us.
//   R19 = R17's per-wave structure exactly, grouped into 512-thread blocks:
//   - 2 blocks/CU x 8 waves = 16 waves/CU (R17 parity)
//   - halo 1.125x (36 staged rows per 32 outputs), 3 barriers per 32 rows
//   - stage: 36 rows/ch split across 8 waves ({wv+8i}, i=0..4, r<36)
//   - compute: 448 of 512 active, 56 cols x 8 tg, TROWS=4, jj=0..7,
//     3 aligned b128/jj, RST=232 (+4-dword shift), lo/hi cndmasks
//   - R18 proved 66816 B static LDS compiles and runs on gfx950
// Kept: channel-phase pipeline (literal phases), XCD swizzle (1792 = 8*224),
// no launch_bounds min-arg, no sched fences.

namespace {

constexpr int Hc = 224, Wc = 224, Cc = 3;
constexpr int HW = Hc * Wc;
constexpr int CHW = Cc * HW;
constexpr int BAND = 32;              // output rows per band (= per block)
constexpr int SROWS = BAND + 4;       // 36 staged rows per (band, channel)
constexpr int RST = 232;              // LDS row stride (dwords); 232%32 = 8
constexpr int BUFD = SROWS * RST;     // 8352 dwords = 33408 B per buffer
constexpr int SPI = Hc / BAND;        // 7 bands (strips) per image
constexpr int BLK = 512;              // 8 waves
constexpr int TROWS = 4;              // output rows per thread

__device__ __forceinline__ void gl_lds16(const float* g, float* l) {
  __builtin_amdgcn_global_load_lds(
      (const __attribute__((address_space(1))) void*)g,
      (__attribute__((address_space(3))) void*)l, 16, 0, 0);
}

__global__ __launch_bounds__(BLK) void conv5x5_r19(
    const float* __restrict__ x, const float* __restrict__ wl,
    const float* __restrict__ bptr, float* __restrict__ out) {
  __shared__ __align__(16) float sm[2 * BUFD];   // 66816 B

  const int tid = threadIdx.x;
  const int lane = tid & 63;
  const int wv = tid >> 6;                 // 0..7

  // Bijective XCD swizzle: 1792 = 8 * 224.
  const int cpx = gridDim.x >> 3;
  const int bid = (blockIdx.x & 7) * cpx + (blockIdx.x >> 3);
  const int n = bid / SPI;                 // image
  const int band = bid % SPI;              // band index (32 rows)

  // Weights: wave-uniform, compile-time offsets -> SGPRs.
  float w[Cc][5][5];
#pragma unroll
  for (int c = 0; c < Cc; ++c)
#pragma unroll
    for (int i = 0; i < 25; ++i) w[c][i / 5][i % 5] = wl[c * 25 + i];
  const float bias = bptr[0];

  const float* xn = x + (size_t)n * CHW;
  float* outn = out + (size_t)n * HW;

  // Compute roles: 448 active = 56 cols x 8 row-groups; thread = 4x4 outputs.
  const bool active = tid < 448;
  const int col = tid % 56;
  const int tg = tid / 56;                 // 0..7
  const bool lo = (col == 0), hi = (col == 55);
  const int rdo = col * 4;                 // read base (dwords) within a row

  float4 acc[TROWS];                       // 4 output rows, live across phases

  // Stage phase P (literal): 36 rows of channel P, band `band`, into buffer
  // P&1. Wave wv owns rows {wv + 8i, r < 36} (wave-uniform guard). LDS dest
  // is the wave-uniform row base (+4-dword shift); HW adds lane*16 (lanes
  // >= 56 masked; row data = dwords 4..227, global dword j at LDS j+4).
  // OOB rows (y pad: band 0 r<2, band 6 r>=34) zero-filled.
#define STAGE_P(P)                                                            \
  do {                                                                        \
    const float* gch_ = xn + (size_t)(P) * HW;                                \
    float* smb_ = sm + ((P) & 1) * BUFD;                                      \
    _Pragma("unroll") for (int i_ = 0; i_ < 5; ++i_) {                        \
      const int r_ = wv + 8 * i_;                                             \
      if (r_ < SROWS) {                                                       \
        const int gy_ = band * BAND - 2 + r_;                                 \
        float* ld_ = smb_ + r_ * RST + 4;                                     \
        if (gy_ >= 0 && gy_ < Hc) {                                           \
          if (lane < 56)                                                      \
            gl_lds16(gch_ + (size_t)gy_ * Wc + lane * 4, ld_);                \
        } else {                                                              \
          if (lane < 56)                                                      \
            *(float4*)(ld_ + lane * 4) = make_float4(0.f, 0.f, 0.f, 0.f);     \
        }                                                                     \
      }                                                                       \
    }                                                                         \
  } while (0)

  // Compute phase P (literal) from buffer P&1. Thread reads LDS rows
  // tg*4 + jj, jj=0..7 (max 35 = SROWS-1); output row r (0..3) taps
  // jj = r..r+4 (ky = jj-r). Window = 3 aligned b128: A @ dword 4c,
  // B @ 4c+4, C @ 4c+8; win[j] = global[4c-2+j] = {A.z,A.w,B.xyzw,C.x,C.y}.
#define COMPUTE_P(P)                                                          \
  do {                                                                        \
    constexpr int ch_ = (P);                                                  \
    const float* smb_ = sm + ((P) & 1) * BUFD;                                \
    if (ch_ == 0) {                                                           \
      _Pragma("unroll") for (int r_ = 0; r_ < TROWS; ++r_)                    \
          acc[r_] = make_float4(0.f, 0.f, 0.f, 0.f);                          \
    }                                                                         \
    if (active) {                                                             \
      _Pragma("unroll") for (int jj_ = 0; jj_ < TROWS + 4; ++jj_) {           \
        const float* rp_ = smb_ + (tg * TROWS + jj_) * RST + rdo;             \
        const float4 A_ = *(const float4*)rp_;                                \
        const float4 B_ = *(const float4*)(rp_ + 4);                          \
        const float4 C_ = *(const float4*)(rp_ + 8);                          \
        float win_[8];                                                        \
        win_[0] = lo ? 0.f : A_.z;                                            \
        win_[1] = lo ? 0.f : A_.w;                                            \
        win_[2] = B_.x; win_[3] = B_.y; win_[4] = B_.z; win_[5] = B_.w;       \
        win_[6] = hi ? 0.f : C_.x;                                            \
        win_[7] = hi ? 0.f : C_.y;                                            \
        _Pragma("unroll") for (int r_ = 0; r_ < TROWS; ++r_) {                \
          if (r_ <= jj_ && jj_ - r_ <= 4) {                                   \
            _Pragma("unroll") for (int kx_ = 0; kx_ < 5; ++kx_) {             \
              const float wv_ = w[ch_][jj_ - r_][kx_];                        \
              acc[r_].x = fmaf(win_[kx_ + 0], wv_, acc[r_].x);                \
              acc[r_].y = fmaf(win_[kx_ + 1], wv_, acc[r_].y);                \
              acc[r_].z = fmaf(win_[kx_ + 2], wv_, acc[r_].z);                \
              acc[r_].w = fmaf(win_[kx_ + 3], wv_, acc[r_].w);                \
            }                                                                 \
          }                                                                   \
        }                                                                     \
      }                                                                       \
      if (ch_ == 2) {                                                         \
        const int gy0_ = band * BAND + tg * TROWS;                            \
        float* op_ = outn + (size_t)gy0_ * Wc + col * 4;                      \
        _Pragma("unroll") for (int r_ = 0; r_ < TROWS; ++r_) {                \
          float4 oo_;                                                         \
          oo_.x = acc[r_].x + bias; oo_.y = acc[r_].y + bias;                 \
          oo_.z = acc[r_].z + bias; oo_.w = acc[r_].w + bias;                 \
          *(float4*)(op_ + (size_t)r_ * Wc) = oo_;                            \
        }                                                                     \
      }                                                                       \
    }                                                                         \
  } while (0)

  // ---- pipeline: stage(P+1) flies under compute(P); 3 barriers total ----
  STAGE_P(0);
  __syncthreads(); STAGE_P(1); COMPUTE_P(0);
  __syncthreads(); STAGE_P(2); COMPUTE_P(1);
  __syncthreads();             COMPUTE_P(2);

#undef STAGE_P
#undef COMPUTE_P
}

}  // namespace

extern "C" void kernel_launch(void* const* d_in, const int* in_sizes, int n_in,
                              void* d_out, int out_size, void* d_ws, size_t ws_size,
                              hipStream_t stream) {
  const float* x  = (const float*)d_in[0];   // [N,3,224,224] f32
  const float* wl = (const float*)d_in[1];   // [1,75] f32
  const float* b  = (const float*)d_in[2];   // [1] f32
  float* out = (float*)d_out;                // [N,224,224] f32

  const int N = out_size / HW;               // 256
  const int nblk = N * SPI;                  // 1792 = 8 * 224

  conv5x5_r19<<<nblk, BLK, 0, stream>>>(x, wl, b, out);
}

// Round 20
// 44.654 us; speedup vs baseline: 1.1358x; 1.0892x over previous
//
#include <hip/hip_runtime.h>

// Conv2d 5x5, C=3, O=1, stride 1, pad 2, N=256, H=W=224, +bias.
// R20 = R17 (45.0us best) with exact-window LDS reads (paired b64).
//   R19 post-mortem: BAND=32 loses even at 16 waves/CU (8-wave barrier
//   coupling) -> R17 geometry is the local optimum. New lever: R17's window
//   reads 3x b128 = 48B for a 32B window (A.zw / C.xy discard half).
//   Window = LDS dwords 4c+2..4c+9 = four 8B-aligned float2 reads at
//   rp+2/+4/+6/+8; LLVM's DS combiner merges pairs into ds_read2_b64:
//   2 instrs, 32B -> LDS pipe -33% bytes/instrs. Lanes c, c+8 differ by
//   32 dwords = 0 mod 32 banks -> 2-way aliasing = free.
// Everything else R17 verbatim: BAND=16, RST=232 (232%32=8), +4-dword
// shifted rows, channel-phase pipeline (literal phases), 3 barriers,
// 4 blocks/CU x 4 waves, XCD swizzle, no launch_bounds min-arg.

namespace {

constexpr int Hc = 224, Wc = 224, Cc = 3;
constexpr int HW = Hc * Wc;
constexpr int CHW = Cc * HW;
constexpr int BAND = 16;              // output rows per band (= per block)
constexpr int SROWS = BAND + 4;       // 20 staged rows per (band, channel)
constexpr int RST = 232;              // LDS row stride (dwords); 232%32 = 8
constexpr int BUFD = SROWS * RST;     // 4640 dwords = 18560 B per buffer
constexpr int SPI = Hc / BAND;        // 14 bands (strips) per image
constexpr int BLK = 256;

__device__ __forceinline__ void gl_lds16(const float* g, float* l) {
  __builtin_amdgcn_global_load_lds(
      (const __attribute__((address_space(1))) void*)g,
      (__attribute__((address_space(3))) void*)l, 16, 0, 0);
}

__global__ __launch_bounds__(BLK) void conv5x5_r20(
    const float* __restrict__ x, const float* __restrict__ wl,
    const float* __restrict__ bptr, float* __restrict__ out) {
  __shared__ __align__(16) float sm[2 * BUFD];   // 37120 B

  const int tid = threadIdx.x;
  const int lane = tid & 63;
  const int wv = tid >> 6;

  // Bijective XCD swizzle: 3584 = 8 * 448.
  const int cpx = gridDim.x >> 3;
  const int bid = (blockIdx.x & 7) * cpx + (blockIdx.x >> 3);
  const int n = bid / SPI;                 // image
  const int band = bid % SPI;              // band index (16 rows)

  // Weights: wave-uniform, compile-time offsets -> SGPRs.
  float w[Cc][5][5];
#pragma unroll
  for (int c = 0; c < Cc; ++c)
#pragma unroll
    for (int i = 0; i < 25; ++i) w[c][i / 5][i % 5] = wl[c * 25 + i];
  const float bias = bptr[0];

  const float* xn = x + (size_t)n * CHW;
  float* outn = out + (size_t)n * HW;

  // Compute roles: 224 threads = 56 cols x 4 row-groups; thread = 4x4 outputs.
  const bool active = tid < 224;
  const int col = tid % 56;
  const int tg = tid / 56;
  const bool lo = (col == 0), hi = (col == 55);
  // Window base (dwords) within a row: global dword g lives at LDS g+4;
  // window = global 4c-2..4c+5 -> LDS 4c+2..4c+9.
  const int rdo = col * 4 + 2;

  float4 acc[4];                           // 4 output rows, live across phases

  // Stage phase P (literal): 20 rows of channel P, band `band`, into buffer
  // P&1. Wave wv owns rows {wv, wv+4, wv+8, wv+12, wv+16}. LDS dest is the
  // wave-uniform row base (+4-dword shift); HW adds lane*16 (lanes >= 56
  // masked; row data = dwords 4..227, global dword j at LDS dword j+4).
  // OOB rows (y pad: band 0 r<2, band 13 r>=18) zero-filled.
#define STAGE_P(P)                                                            \
  do {                                                                        \
    const float* gch_ = xn + (size_t)(P) * HW;                                \
    float* smb_ = sm + ((P) & 1) * BUFD;                                      \
    _Pragma("unroll") for (int i_ = 0; i_ < 5; ++i_) {                        \
      const int r_ = wv + 4 * i_;                                             \
      const int gy_ = band * BAND - 2 + r_;                                   \
      float* ld_ = smb_ + r_ * RST + 4;                                       \
      if (gy_ >= 0 && gy_ < Hc) {                                             \
        if (lane < 56)                                                        \
          gl_lds16(gch_ + (size_t)gy_ * Wc + lane * 4, ld_);                  \
      } else {                                                                \
        if (lane < 56)                                                        \
          *(float4*)(ld_ + lane * 4) = make_float4(0.f, 0.f, 0.f, 0.f);       \
      }                                                                       \
    }                                                                         \
  } while (0)

  // Compute phase P (literal) from buffer P&1. Thread reads LDS rows
  // tg*4 + jj, jj=0..7; output row r (0..3) taps jj = r..r+4 (ky = jj-r).
  // Window = four 8B float2 reads at rp, rp+2, rp+4, rp+6 (rp = row + rdo);
  // adjacent pairs merge into ds_read2_b64. win[j] = global[4c-2+j] =
  // {d0.xy, d1.xy, d2.xy, d3.xy}; lo masks win[0,1] (left pad garbage),
  // hi masks win[6,7] (right pad garbage).
#define COMPUTE_P(P)                                                          \
  do {                                                                        \
    constexpr int ch_ = (P);                                                  \
    const float* smb_ = sm + ((P) & 1) * BUFD;                                \
    if (ch_ == 0) {                                                           \
      _Pragma("unroll") for (int r_ = 0; r_ < 4; ++r_)                        \
          acc[r_] = make_float4(0.f, 0.f, 0.f, 0.f);                          \
    }                                                                         \
    if (active) {                                                             \
      _Pragma("unroll") for (int jj_ = 0; jj_ < 8; ++jj_) {                   \
        const float* rp_ = smb_ + (tg * 4 + jj_) * RST + rdo;                 \
        const float2 d0_ = *(const float2*)(rp_);                             \
        const float2 d1_ = *(const float2*)(rp_ + 2);                         \
        const float2 d2_ = *(const float2*)(rp_ + 4);                         \
        const float2 d3_ = *(const float2*)(rp_ + 6);                         \
        float win_[8];                                                        \
        win_[0] = lo ? 0.f : d0_.x;                                           \
        win_[1] = lo ? 0.f : d0_.y;                                           \
        win_[2] = d1_.x; win_[3] = d1_.y;                                     \
        win_[4] = d2_.x; win_[5] = d2_.y;                                     \
        win_[6] = hi ? 0.f : d3_.x;                                           \
        win_[7] = hi ? 0.f : d3_.y;                                           \
        _Pragma("unroll") for (int r_ = 0; r_ < 4; ++r_) {                    \
          if (r_ <= jj_ && jj_ - r_ <= 4) {                                   \
            _Pragma("unroll") for (int kx_ = 0; kx_ < 5; ++kx_) {             \
              const float wv_ = w[ch_][jj_ - r_][kx_];                        \
              acc[r_].x = fmaf(win_[kx_ + 0], wv_, acc[r_].x);                \
              acc[r_].y = fmaf(win_[kx_ + 1], wv_, acc[r_].y);                \
              acc[r_].z = fmaf(win_[kx_ + 2], wv_, acc[r_].z);                \
              acc[r_].w = fmaf(win_[kx_ + 3], wv_, acc[r_].w);                \
            }                                                                 \
          }                                                                   \
        }                                                                     \
      }                                                                       \
      if (ch_ == 2) {                                                         \
        const int gy0_ = band * BAND + tg * 4;                                \
        float* op_ = outn + (size_t)gy0_ * Wc + col * 4;                      \
        _Pragma("unroll") for (int r_ = 0; r_ < 4; ++r_) {                    \
          float4 oo_;                                                         \
          oo_.x = acc[r_].x + bias; oo_.y = acc[r_].y + bias;                 \
          oo_.z = acc[r_].z + bias; oo_.w = acc[r_].w + bias;                 \
          *(float4*)(op_ + (size_t)r_ * Wc) = oo_;                            \
        }                                                                     \
      }                                                                       \
    }                                                                         \
  } while (0)

  // ---- pipeline: stage(P+1) flies under compute(P); 3 barriers total ----
  STAGE_P(0);
  __syncthreads(); STAGE_P(1); COMPUTE_P(0);
  __syncthreads(); STAGE_P(2); COMPUTE_P(1);
  __syncthreads();             COMPUTE_P(2);

#undef STAGE_P
#undef COMPUTE_P
}

}  // namespace

extern "C" void kernel_launch(void* const* d_in, const int* in_sizes, int n_in,
                              void* d_out, int out_size, void* d_ws, size_t ws_size,
                              hipStream_t stream) {
  const float* x  = (const float*)d_in[0];   // [N,3,224,224] f32
  const float* wl = (const float*)d_in[1];   // [1,75] f32
  const float* b  = (const float*)d_in[2];   // [1] f32
  float* out = (float*)d_out;                // [N,224,224] f32

  const int N = out_size / HW;               // 256
  const int nblk = N * SPI;                  // 3584 = 8 * 448

  conv5x5_r20<<<nblk, BLK, 0, stream>>>(x, wl, b, out);
}

// Round 21
// 42.538 us; speedup vs baseline: 1.1923x; 1.0497x over previous
//
#include <hip/hip_runtime.h>

// Conv2d 5x5, C=3, O=1, stride 1, pad 2, N=256, H=W=224, +bias.
// R21 = R20 with a full-thread compute mapping (no idle lanes).
//   R20 accounting: per SIMD per phase, VALU demand (4 waves x 400 FMA x
//   2cyc = 3200 cyc) > phase duration (~2550 cyc) -> VALU-issue bound.
//   R20 wasted 12.5% of issue slots: 224/256 active meant wave 3 ran
//   half-masked. 224 = 7 x 32, so remap: 256 threads = 32 col-groups
//   (7 outputs wide) x 8 row-groups (2 rows). FMA/thread/phase 400 -> 350.
//   Window = 11 floats (global 7g-2 .. 7g+8) read as dword pairs
//   (ds_read2_b32 takes two arbitrary dword offsets; no alignment issue).
//   Read bases stride 7 dwords across lanes; gcd(7,32)=1 -> conflict-free.
// Kept from R20/R17: BAND=16, RST=232 (232%32=8), +4-dword shifted rows,
// channel-phase pipeline (literal phases), 3 barriers, stage via gl_lds16
// (wave-uniform dest, lane<56), 4 blocks/CU, XCD swizzle, no launch_bounds
// min-arg.

namespace {

constexpr int Hc = 224, Wc = 224, Cc = 3;
constexpr int HW = Hc * Wc;
constexpr int CHW = Cc * HW;
constexpr int BAND = 16;              // output rows per band (= per block)
constexpr int SROWS = BAND + 4;       // 20 staged rows per (band, channel)
constexpr int RST = 232;              // LDS row stride (dwords); 232%32 = 8
constexpr int BUFD = SROWS * RST;     // 4640 dwords = 18560 B per buffer
constexpr int SPI = Hc / BAND;        // 14 bands (strips) per image
constexpr int BLK = 256;

__device__ __forceinline__ void gl_lds16(const float* g, float* l) {
  __builtin_amdgcn_global_load_lds(
      (const __attribute__((address_space(1))) void*)g,
      (__attribute__((address_space(3))) void*)l, 16, 0, 0);
}

__global__ __launch_bounds__(BLK) void conv5x5_r21(
    const float* __restrict__ x, const float* __restrict__ wl,
    const float* __restrict__ bptr, float* __restrict__ out) {
  __shared__ __align__(16) float sm[2 * BUFD];   // 37120 B

  const int tid = threadIdx.x;
  const int lane = tid & 63;
  const int wv = tid >> 6;

  // Bijective XCD swizzle: 3584 = 8 * 448.
  const int cpx = gridDim.x >> 3;
  const int bid = (blockIdx.x & 7) * cpx + (blockIdx.x >> 3);
  const int n = bid / SPI;                 // image
  const int band = bid % SPI;              // band index (16 rows)

  // Weights: wave-uniform, compile-time offsets -> SGPRs.
  float w[Cc][5][5];
#pragma unroll
  for (int c = 0; c < Cc; ++c)
#pragma unroll
    for (int i = 0; i < 25; ++i) w[c][i / 5][i % 5] = wl[c * 25 + i];
  const float bias = bptr[0];

  const float* xn = x + (size_t)n * CHW;
  float* outn = out + (size_t)n * HW;

  // Compute roles: ALL 256 threads = 32 col-groups (7 wide) x 8 row-groups
  // (2 rows). Window for group g = global x in [7g-2, 7g+8] = LDS dwords
  // [7g+2, 7g+12] (global dword j lives at LDS j+4).
  const int g = tid & 31;                  // col group, x0 = 7g
  const int tg = tid >> 5;                 // row group 0..7
  const bool lo = (g == 0), hi = (g == 31);
  const int rdo = g * 7 + 2;               // window base (dwords) within row

  float acc[2][7];                         // 2 rows x 7 cols, static indexed

  // Stage phase P (literal): 20 rows of channel P, band `band`, into buffer
  // P&1. Wave wv owns rows {wv, wv+4, wv+8, wv+12, wv+16}. LDS dest is the
  // wave-uniform row base (+4-dword shift); HW adds lane*16 (lanes >= 56
  // masked; row data = dwords 4..227, global dword j at LDS dword j+4).
  // OOB rows (y pad: band 0 r<2, band 13 r>=18) zero-filled.
#define STAGE_P(P)                                                            \
  do {                                                                        \
    const float* gch_ = xn + (size_t)(P) * HW;                                \
    float* smb_ = sm + ((P) & 1) * BUFD;                                      \
    _Pragma("unroll") for (int i_ = 0; i_ < 5; ++i_) {                        \
      const int r_ = wv + 4 * i_;                                             \
      const int gy_ = band * BAND - 2 + r_;                                   \
      float* ld_ = smb_ + r_ * RST + 4;                                       \
      if (gy_ >= 0 && gy_ < Hc) {                                             \
        if (lane < 56)                                                        \
          gl_lds16(gch_ + (size_t)gy_ * Wc + lane * 4, ld_);                  \
      } else {                                                                \
        if (lane < 56)                                                        \
          *(float4*)(ld_ + lane * 4) = make_float4(0.f, 0.f, 0.f, 0.f);       \
      }                                                                       \
    }                                                                         \
  } while (0)

  // Compute phase P (literal) from buffer P&1. Thread reads LDS rows
  // tg*2 + jj, jj=0..5; output row r (0..1) taps jj = r..r+4 (ky = jj-r).
  // Window win[j] = global[7g-2+j], j=0..10, read as dword pairs
  // (ds_read2_b32); lo masks win[0,1], hi masks win[9,10] (pad garbage).
#define COMPUTE_P(P)                                                          \
  do {                                                                        \
    constexpr int ch_ = (P);                                                  \
    const float* smb_ = sm + ((P) & 1) * BUFD;                                \
    if (ch_ == 0) {                                                           \
      _Pragma("unroll") for (int r_ = 0; r_ < 2; ++r_)                        \
          _Pragma("unroll") for (int c_ = 0; c_ < 7; ++c_)                    \
              acc[r_][c_] = 0.f;                                              \
    }                                                                         \
    _Pragma("unroll") for (int jj_ = 0; jj_ < 6; ++jj_) {                     \
      const float* rp_ = smb_ + (tg * 2 + jj_) * RST + rdo;                   \
      float win_[11];                                                         \
      _Pragma("unroll") for (int j_ = 0; j_ < 11; ++j_) win_[j_] = rp_[j_];   \
      win_[0] = lo ? 0.f : win_[0];                                           \
      win_[1] = lo ? 0.f : win_[1];                                           \
      win_[9] = hi ? 0.f : win_[9];                                           \
      win_[10] = hi ? 0.f : win_[10];                                         \
      _Pragma("unroll") for (int r_ = 0; r_ < 2; ++r_) {                      \
        if (r_ <= jj_ && jj_ - r_ <= 4) {                                     \
          _Pragma("unroll") for (int kx_ = 0; kx_ < 5; ++kx_) {               \
            const float wv_ = w[ch_][jj_ - r_][kx_];                          \
            _Pragma("unroll") for (int c_ = 0; c_ < 7; ++c_) {                \
              acc[r_][c_] = fmaf(win_[c_ + kx_], wv_, acc[r_][c_]);           \
            }                                                                 \
          }                                                                   \
        }                                                                     \
      }                                                                       \
    }                                                                         \
    if (ch_ == 2) {                                                           \
      _Pragma("unroll") for (int r_ = 0; r_ < 2; ++r_) {                      \
        const int gy_ = band * BAND + tg * 2 + r_;                            \
        float* op_ = outn + (size_t)gy_ * Wc + g * 7;                         \
        _Pragma("unroll") for (int c_ = 0; c_ < 7; ++c_)                      \
            op_[c_] = acc[r_][c_] + bias;                                     \
      }                                                                       \
    }                                                                         \
  } while (0)

  // ---- pipeline: stage(P+1) flies under compute(P); 3 barriers total ----
  STAGE_P(0);
  __syncthreads(); STAGE_P(1); COMPUTE_P(0);
  __syncthreads(); STAGE_P(2); COMPUTE_P(1);
  __syncthreads();             COMPUTE_P(2);

#undef STAGE_P
#undef COMPUTE_P
}

}  // namespace

extern "C" void kernel_launch(void* const* d_in, const int* in_sizes, int n_in,
                              void* d_out, int out_size, void* d_ws, size_t ws_size,
                              hipStream_t stream) {
  const float* x  = (const float*)d_in[0];   // [N,3,224,224] f32
  const float* wl = (const float*)d_in[1];   // [1,75] f32
  const float* b  = (const float*)d_in[2];   // [1] f32
  float* out = (float*)d_out;                // [N,224,224] f32

  const int N = out_size / HW;               // 256
  const int nblk = N * SPI;                  // 3584 = 8 * 448

  conv5x5_r21<<<nblk, BLK, 0, stream>>>(x, wl, b, out);
}